// Round 10
// baseline (68.389 us; speedup 1.0000x reference)
//
#include <hip/hip_runtime.h>

#define NB 128
#define NS 65536

typedef __attribute__((address_space(3))) float lds_float;
typedef __attribute__((address_space(1))) const float gbl_float;

// ---- VALU-pipe cross-lane helpers -----------------------------------------
template <int CTRL>
__device__ __forceinline__ float dppmov(float x) {
  // DPP move (VALU pipe): quad_perm or row_ror, all lanes valid
  return __int_as_float(__builtin_amdgcn_update_dpp(
      0, __float_as_int(x), CTRL, 0xF, 0xF, false));
}
template <int OFF>
__device__ __forceinline__ float dswz(float x) {
  return __int_as_float(__builtin_amdgcn_ds_swizzle(__float_as_int(x), OFF));
}

// In-wave 256-point Walsh-Hadamard transform (unnormalized).
// Element e = 4*lane + q. Bits 0,1 in registers; lane bits:
//  xor1 quad_perm 0xB1; xor2 quad_perm 0x4E; xor4 ds_swizzle (only DS stage);
//  xor8 DPP row_ror:8 ((i+8)%16 == i^8 within a row); xor16/32 permlane swaps.
__device__ __forceinline__ void wht256(float (&xr)[4], float (&xi)[4], int lane) {
  {
    float t;
    t = xr[0]; xr[0] = t + xr[1]; xr[1] = t - xr[1];
    t = xr[2]; xr[2] = t + xr[3]; xr[3] = t - xr[3];
    t = xi[0]; xi[0] = t + xi[1]; xi[1] = t - xi[1];
    t = xi[2]; xi[2] = t + xi[3]; xi[3] = t - xi[3];
    t = xr[0]; xr[0] = t + xr[2]; xr[2] = t - xr[2];
    t = xr[1]; xr[1] = t + xr[3]; xr[3] = t - xr[3];
    t = xi[0]; xi[0] = t + xi[2]; xi[2] = t - xi[2];
    t = xi[1]; xi[1] = t + xi[3]; xi[3] = t - xi[3];
  }
  const float s1  = (lane & 1)  ? -1.f : 1.f;
  const float s2  = (lane & 2)  ? -1.f : 1.f;
  const float s4  = (lane & 4)  ? -1.f : 1.f;
  const float s8  = (lane & 8)  ? -1.f : 1.f;
  const float s16 = (lane & 16) ? -1.f : 1.f;
  const float s32 = (lane & 32) ? -1.f : 1.f;
#pragma unroll
  for (int q = 0; q < 4; ++q) {
    xr[q] = fmaf(s1, xr[q], dppmov<0xB1>(xr[q]));
    xi[q] = fmaf(s1, xi[q], dppmov<0xB1>(xi[q]));
  }
#pragma unroll
  for (int q = 0; q < 4; ++q) {
    xr[q] = fmaf(s2, xr[q], dppmov<0x4E>(xr[q]));
    xi[q] = fmaf(s2, xi[q], dppmov<0x4E>(xi[q]));
  }
#pragma unroll
  for (int q = 0; q < 4; ++q) {
    xr[q] = fmaf(s4, xr[q], dswz<0x101F>(xr[q]));
    xi[q] = fmaf(s4, xi[q], dswz<0x101F>(xi[q]));
  }
#pragma unroll
  for (int q = 0; q < 4; ++q) {
    xr[q] = fmaf(s8, xr[q], dppmov<0x128>(xr[q]));  // row_ror:8 == lane^8
    xi[q] = fmaf(s8, xi[q], dppmov<0x128>(xi[q]));
  }
#pragma unroll
  for (int q = 0; q < 4; ++q) {
    {
      auto r = __builtin_amdgcn_permlane16_swap(__float_as_uint(xr[q]),
                                                __float_as_uint(xr[q]), false, false);
      xr[q] = fmaf(s16, __uint_as_float(r[1]), __uint_as_float(r[0]));
    }
    {
      auto r = __builtin_amdgcn_permlane16_swap(__float_as_uint(xi[q]),
                                                __float_as_uint(xi[q]), false, false);
      xi[q] = fmaf(s16, __uint_as_float(r[1]), __uint_as_float(r[0]));
    }
  }
#pragma unroll
  for (int q = 0; q < 4; ++q) {
    {
      auto r = __builtin_amdgcn_permlane32_swap(__float_as_uint(xr[q]),
                                                __float_as_uint(xr[q]), false, false);
      xr[q] = fmaf(s32, __uint_as_float(r[1]), __uint_as_float(r[0]));
    }
    {
      auto r = __builtin_amdgcn_permlane32_swap(__float_as_uint(xi[q]),
                                                __float_as_uint(xi[q]), false, false);
      xi[q] = fmaf(s32, __uint_as_float(r[1]), __uint_as_float(r[0]));
    }
  }
}

// K1: A_hi = WHT·diag(ph_hi)·WHT along hi. 32-lo x 256-hi tile, 1024 thr.
// Staging: async global_load_lds (width 4) with PRE-SWIZZLED global source:
//   LDS[j][c] = in[j][lo0 + (c ^ s(j))], s(j) = (j>>2)&31  -> all later column
// accesses are 2 lanes/bank (free). Compute is in-place per lo column (wave-
// private slots). Drain writes T[b][m_hi][lo] complex in 256B row chunks.
__global__ __launch_bounds__(1024, 8) void k1_ahi(const float* __restrict__ sre,
                                                  const float* __restrict__ sim,
                                                  const float* __restrict__ thetas,
                                                  float* __restrict__ T,
                                                  float* __restrict__ partial) {
  __shared__ float SR[256][32];
  __shared__ float SI[256][32];
  __shared__ float2 phh4[64];
  __shared__ float2 phHQ[4];
  __shared__ float red[16];
  const int bid = blockIdx.x;
  const int b = bid >> 3, tile = bid & 7;
  const int lo0 = tile * 32;
  const int tid = threadIdx.x, lane = tid & 63, w = tid >> 6;
  const float* pre = sre + ((size_t)b << 16);
  const float* pim = sim + ((size_t)b << 16);

  // ---- async staging: waves 0-7 stage SR, waves 8-15 stage SI ----
  {
    const float* src = (w < 8) ? pre : pim;
    float* dst0 = (w < 8) ? &SR[0][0] : &SI[0][0];
    const int w8 = w & 7;
    const int cl = lane & 31, half = lane >> 5;
#pragma unroll
    for (int i = 0; i < 16; ++i) {
      const int jb = w8 * 32 + i * 2;          // even: jb and jb+1 share jb>>2
      const int s = (jb >> 2) & 31;
      const float* gp = src + (jb + half) * 256 + lo0 + (cl ^ s);
      __builtin_amdgcn_global_load_lds((gbl_float*)gp,
                                       (lds_float*)(dst0 + jb * 32), 4, 0, 0);
    }
  }
  // ---- phase tables straight from global (L2-hot), overlap with staging ----
  if (tid < 64) {
    const float* tb = thetas + b * 16;
    float a = 0.f;
#pragma unroll
    for (int i = 0; i < 6; ++i)
      if ((tid >> (5 - i)) & 1) a += tb[i];
    phh4[tid] = make_float2(cosf(0.5f * a), -sinf(0.5f * a));
    if (tid < 4) {
      float aq = 0.f;
      if (tid & 1) aq += tb[7];
      if (tid & 2) aq += tb[6];
      phHQ[tid] = make_float2(cosf(0.5f * aq), -sinf(0.5f * aq));
    }
  }
  __syncthreads();  // drains global_load_lds (vmcnt) + table visibility

  // ---- compute: wave w owns lo columns 2w, 2w+1 (in-place in LDS) ----
  float acc = 0.f;
  const int sw = lane & 31;  // == ((4*lane+q)>>2)&31 for all q
#pragma unroll
  for (int r = 0; r < 2; ++r) {
    const int ll = w * 2 + r;
    const int col = ll ^ sw;
    float xr[4], xi[4];
#pragma unroll
    for (int q = 0; q < 4; ++q) {
      xr[q] = SR[4 * lane + q][col];
      xi[q] = SI[4 * lane + q][col];
    }
    acc += xr[0]*xr[0]+xr[1]*xr[1]+xr[2]*xr[2]+xr[3]*xr[3]
         + xi[0]*xi[0]+xi[1]*xi[1]+xi[2]*xi[2]+xi[3]*xi[3];
    wht256(xr, xi, lane);
    const float2 p4 = phh4[lane];
#pragma unroll
    for (int q = 0; q < 4; ++q) {
      const float2 pq = phHQ[q];
      const float pr = p4.x * pq.x - p4.y * pq.y;
      const float pi = p4.x * pq.y + p4.y * pq.x;
      const float ur = xr[q], ui = xi[q];
      xr[q] = ur * pr - ui * pi;
      xi[q] = ur * pi + ui * pr;
    }
    wht256(xr, xi, lane);
#pragma unroll
    for (int q = 0; q < 4; ++q) {
      SR[4 * lane + q][col] = xr[q];
      SI[4 * lane + q][col] = xi[q];
    }
  }
#pragma unroll
  for (int m = 32; m >= 1; m >>= 1) acc += __shfl_xor(acc, m, 64);
  if (lane == 0) red[w] = acc;
  __syncthreads();
  if (tid == 0) {
    float sm = 0.f;
#pragma unroll
    for (int k = 0; k < 16; ++k) sm += red[k];
    partial[bid] = sm;
  }
  // ---- drain: T[b][m][lo] complex; 8 threads per m row -> 256B chunks ----
  float* Tb = T + ((size_t)b << 17);
  const int chunk = tid & 7;
#pragma unroll
  for (int it = 0; it < 2; ++it) {
    const int m = (tid >> 3) + it * 128;
    const int s = (m >> 2) & 31;
    const int c0 = (4 * chunk) ^ s, c1 = (4 * chunk + 1) ^ s,
              c2 = (4 * chunk + 2) ^ s, c3 = (4 * chunk + 3) ^ s;
    float* dst = Tb + ((size_t)m << 9) + (size_t)(lo0 + 4 * chunk) * 2;
    *reinterpret_cast<float4*>(dst) =
        make_float4(SR[m][c0], SI[m][c0], SR[m][c1], SI[m][c1]);
    *reinterpret_cast<float4*>(dst + 4) =
        make_float4(SR[m][c2], SI[m][c2], SR[m][c3], SI[m][c3]);
  }
}

// K2: A_lo = WHT·diag(ph_lo)·WHT along contiguous lo axis, |.|^2 * iv,
// permuted scatter out[srow[m_hi] ^ sloL[lane] ^ sloQ[q]] (lo-varying = the
// empirically fast orientation). GF(2)/phase linearity factors all tables to
// one conflict-free LDS read per lane. XCD swizzle: each XCD owns 16 batches.
__global__ __launch_bounds__(256, 8) void k2_alo_scatter(const float* __restrict__ T,
                                                         const float* __restrict__ thetas,
                                                         const int* __restrict__ cnot,
                                                         const float* __restrict__ partial,
                                                         float* __restrict__ outp) {
  __shared__ float2 phl4[64];
  __shared__ float2 phLQ[4];
  __shared__ int sloL[64];
  __shared__ int tj[16];
  __shared__ int srow16[16];
  __shared__ float th[16];
  __shared__ float shinv;
  const int bid = blockIdx.x;
  const int x = bid & 7, s2 = bid >> 3;
  const int b = x * 16 + (s2 >> 4), tile = s2 & 15;
  const int tid = threadIdx.x, lane = tid & 63, w = tid >> 6;
  if (tid < 16) {
    th[tid] = thetas[b * 16 + tid];
    int v = 0;
#pragma unroll
    for (int i = 0; i < 16; ++i) v |= ((cnot[1 << i] >> tid) & 1) << i;
    tj[tid] = v;
  }
  if (tid == 0) {
    float sum = 0.f;
#pragma unroll
    for (int k = 0; k < 8; ++k) sum += partial[b * 8 + k];
    shinv = 1.0f / (sum * 4294967296.0f);  // fold 2^-32 WHT scaling + 1/norm^2
  }
  __syncthreads();
  if (tid < 64) {
    float a = 0.f;
#pragma unroll
    for (int i = 0; i < 6; ++i)
      if ((tid >> (5 - i)) & 1) a += th[8 + i];
    phl4[tid] = make_float2(cosf(0.5f * a), -sinf(0.5f * a));
    int v = 0;
#pragma unroll
    for (int bb = 0; bb < 6; ++bb)
      if ((tid >> bb) & 1) v ^= tj[2 + bb];
    sloL[tid] = v;
    if (tid < 4) {
      float aq = 0.f;
      if (tid & 1) aq += th[15];
      if (tid & 2) aq += th[14];
      phLQ[tid] = make_float2(cosf(0.5f * aq), -sinf(0.5f * aq));
    }
  }
  if (tid < 16) {
    const int mh = tile * 16 + tid;
    int v = 0;
#pragma unroll
    for (int bb = 0; bb < 8; ++bb)
      if ((mh >> bb) & 1) v ^= tj[8 + bb];
    srow16[tid] = v;
  }
  __syncthreads();
  const float* Tb = T + ((size_t)b << 17);
  float* ob = outp + ((size_t)b << 16);
  const float iv = shinv;
  const float2 p4 = phl4[lane];
  const int sL = sloL[lane];
  const int sq1 = tj[0], sq2 = tj[1], sq3 = tj[0] ^ tj[1];
  float2 p4q[4];
#pragma unroll
  for (int q = 0; q < 4; ++q) {
    const float2 pq = phLQ[q];
    p4q[q].x = p4.x * pq.x - p4.y * pq.y;
    p4q[q].y = p4.x * pq.y + p4.y * pq.x;
  }
#pragma unroll
  for (int r = 0; r < 4; ++r) {
    const int rl = w * 4 + r;
    const int mh = tile * 16 + rl;
    const float4 va = *reinterpret_cast<const float4*>(Tb + ((size_t)mh << 9) + lane * 8);
    const float4 vb = *reinterpret_cast<const float4*>(Tb + ((size_t)mh << 9) + lane * 8 + 4);
    float xr[4] = {va.x, va.z, vb.x, vb.z};
    float xi[4] = {va.y, va.w, vb.y, vb.w};
    wht256(xr, xi, lane);
#pragma unroll
    for (int q = 0; q < 4; ++q) {
      const float ur = xr[q], ui = xi[q];
      xr[q] = ur * p4q[q].x - ui * p4q[q].y;
      xi[q] = ur * p4q[q].y + ui * p4q[q].x;
    }
    wht256(xr, xi, lane);
    const int base = srow16[rl] ^ sL;
    ob[base]       = (xr[0] * xr[0] + xi[0] * xi[0]) * iv;
    ob[base ^ sq1] = (xr[1] * xr[1] + xi[1] * xi[1]) * iv;
    ob[base ^ sq2] = (xr[2] * xr[2] + xi[2] * xi[2]) * iv;
    ob[base ^ sq3] = (xr[3] * xr[3] + xi[3] * xi[3]) * iv;
  }
}

extern "C" void kernel_launch(void* const* d_in, const int* in_sizes, int n_in,
                              void* d_out, int out_size, void* d_ws, size_t ws_size,
                              hipStream_t stream) {
  const float* sre = (const float*)d_in[0];
  const float* sim = (const float*)d_in[1];
  const float* thetas = (const float*)d_in[2];
  const int* cnot = (const int*)d_in[3];
  float* outp = (float*)d_out;
  char* w = (char*)d_ws;
  const size_t CPLANE = (size_t)NB * NS * 2 * sizeof(float);  // 64 MB complex
  if (ws_size < CPLANE + 8192) return;  // need 64 MB scratch + partials
  float* T = (float*)(w);
  float* partial = (float*)(w + CPLANE);  // 1024 floats

  hipLaunchKernelGGL(k1_ahi, dim3(1024), dim3(1024), 0, stream, sre, sim, thetas, T, partial);
  hipLaunchKernelGGL(k2_alo_scatter, dim3(2048), dim3(256), 0, stream, T, thetas, cnot, partial, outp);
}

// Round 11
// 62.655 us; speedup vs baseline: 1.0915x; 1.0915x over previous
//
#include <hip/hip_runtime.h>

#define NB 128
#define NS 65536

// ---- VALU-pipe cross-lane helpers -----------------------------------------
template <int CTRL>
__device__ __forceinline__ float dppmov(float x) {
  // DPP move (VALU pipe): quad_perm or row_ror, all lanes valid
  return __int_as_float(__builtin_amdgcn_update_dpp(
      0, __float_as_int(x), CTRL, 0xF, 0xF, false));
}
template <int OFF>
__device__ __forceinline__ float dswz(float x) {
  return __int_as_float(__builtin_amdgcn_ds_swizzle(__float_as_int(x), OFF));
}

// In-wave 256-point Walsh-Hadamard transform (unnormalized).
// Element e = 4*lane + q. Bits 0,1 in registers; lane bits:
//  xor1 quad_perm 0xB1; xor2 quad_perm 0x4E; xor4 ds_swizzle (only DS stage);
//  xor8 DPP row_ror:8 ((i+8)%16 == i^8 within a 16-lane row);
//  xor16/xor32 permlane16/32_swap (VALU). Validated in R10 (absmax 4.77e-7).
__device__ __forceinline__ void wht256(float (&xr)[4], float (&xi)[4], int lane) {
  {
    float t;
    t = xr[0]; xr[0] = t + xr[1]; xr[1] = t - xr[1];
    t = xr[2]; xr[2] = t + xr[3]; xr[3] = t - xr[3];
    t = xi[0]; xi[0] = t + xi[1]; xi[1] = t - xi[1];
    t = xi[2]; xi[2] = t + xi[3]; xi[3] = t - xi[3];
    t = xr[0]; xr[0] = t + xr[2]; xr[2] = t - xr[2];
    t = xr[1]; xr[1] = t + xr[3]; xr[3] = t - xr[3];
    t = xi[0]; xi[0] = t + xi[2]; xi[2] = t - xi[2];
    t = xi[1]; xi[1] = t + xi[3]; xi[3] = t - xi[3];
  }
  const float s1  = (lane & 1)  ? -1.f : 1.f;
  const float s2  = (lane & 2)  ? -1.f : 1.f;
  const float s4  = (lane & 4)  ? -1.f : 1.f;
  const float s8  = (lane & 8)  ? -1.f : 1.f;
  const float s16 = (lane & 16) ? -1.f : 1.f;
  const float s32 = (lane & 32) ? -1.f : 1.f;
#pragma unroll
  for (int q = 0; q < 4; ++q) {
    xr[q] = fmaf(s1, xr[q], dppmov<0xB1>(xr[q]));
    xi[q] = fmaf(s1, xi[q], dppmov<0xB1>(xi[q]));
  }
#pragma unroll
  for (int q = 0; q < 4; ++q) {
    xr[q] = fmaf(s2, xr[q], dppmov<0x4E>(xr[q]));
    xi[q] = fmaf(s2, xi[q], dppmov<0x4E>(xi[q]));
  }
#pragma unroll
  for (int q = 0; q < 4; ++q) {
    xr[q] = fmaf(s4, xr[q], dswz<0x101F>(xr[q]));
    xi[q] = fmaf(s4, xi[q], dswz<0x101F>(xi[q]));
  }
#pragma unroll
  for (int q = 0; q < 4; ++q) {
    xr[q] = fmaf(s8, xr[q], dppmov<0x128>(xr[q]));  // row_ror:8 == lane^8
    xi[q] = fmaf(s8, xi[q], dppmov<0x128>(xi[q]));
  }
#pragma unroll
  for (int q = 0; q < 4; ++q) {
    {
      auto r = __builtin_amdgcn_permlane16_swap(__float_as_uint(xr[q]),
                                                __float_as_uint(xr[q]), false, false);
      xr[q] = fmaf(s16, __uint_as_float(r[1]), __uint_as_float(r[0]));
    }
    {
      auto r = __builtin_amdgcn_permlane16_swap(__float_as_uint(xi[q]),
                                                __float_as_uint(xi[q]), false, false);
      xi[q] = fmaf(s16, __uint_as_float(r[1]), __uint_as_float(r[0]));
    }
  }
#pragma unroll
  for (int q = 0; q < 4; ++q) {
    {
      auto r = __builtin_amdgcn_permlane32_swap(__float_as_uint(xr[q]),
                                                __float_as_uint(xr[q]), false, false);
      xr[q] = fmaf(s32, __uint_as_float(r[1]), __uint_as_float(r[0]));
    }
    {
      auto r = __builtin_amdgcn_permlane32_swap(__float_as_uint(xi[q]),
                                                __float_as_uint(xi[q]), false, false);
      xi[q] = fmaf(s32, __uint_as_float(r[1]), __uint_as_float(r[0]));
    }
  }
}

// K1: A_hi = WHT·diag(ph_hi)·WHT along the hi axis. 32-lo x 256-hi tile,
// 1024 threads (16 waves x 2 rows). Global reads are exact 128B lines per
// hi-row, all 4 float4s prefetched to registers before the LDS-transpose
// writes (4KB/wave in flight). LDS transpose in/out; T[b][m_hi][lo] written
// complex-interleaved. 66.5KB LDS -> 2 blocks/CU = 32 waves/CU nominal.
__global__ __launch_bounds__(1024, 8) void k1_ahi(const float* __restrict__ sre,
                                                  const float* __restrict__ sim,
                                                  const float* __restrict__ thetas,
                                                  float* __restrict__ T,
                                                  float* __restrict__ partial) {
  __shared__ float sr[32][260];
  __shared__ float si[32][260];
  __shared__ float2 phh4[64];
  __shared__ float2 phHQ[4];
  __shared__ float th[16];
  __shared__ float red[16];
  const int bid = blockIdx.x;
  const int b = bid >> 3, tile = bid & 7;
  const int lo0 = tile * 32;
  const int tid = threadIdx.x, lane = tid & 63, w = tid >> 6;
  if (tid < 16) th[tid] = thetas[b * 16 + tid];
  __syncthreads();
  if (tid < 64) {
    // phase tables over hi index h = (l<<2)|q; ang_hi(h) = sum th[7-t] over set bits t
    float a = 0.f;
#pragma unroll
    for (int i = 0; i < 6; ++i)
      if ((tid >> (5 - i)) & 1) a += th[i];
    phh4[tid] = make_float2(cosf(0.5f * a), -sinf(0.5f * a));
    if (tid < 4) {
      float aq = 0.f;
      if (tid & 1) aq += th[7];
      if (tid & 2) aq += th[6];
      phHQ[tid] = make_float2(cosf(0.5f * aq), -sinf(0.5f * aq));
    }
  }
  // load phase: prefetch 4 float4s (both j-rows, re+im), then LDS transpose
  const float* pre = sre + ((size_t)b << 16);
  const float* pim = sim + ((size_t)b << 16);
  const int c = tid & 7, jr = tid >> 3;
  const int j0 = jr, j1 = jr + 128;
  const float4 vr0 = *reinterpret_cast<const float4*>(pre + j0 * 256 + lo0 + c * 4);
  const float4 vi0 = *reinterpret_cast<const float4*>(pim + j0 * 256 + lo0 + c * 4);
  const float4 vr1 = *reinterpret_cast<const float4*>(pre + j1 * 256 + lo0 + c * 4);
  const float4 vi1 = *reinterpret_cast<const float4*>(pim + j1 * 256 + lo0 + c * 4);
  float acc = vr0.x*vr0.x + vr0.y*vr0.y + vr0.z*vr0.z + vr0.w*vr0.w
            + vi0.x*vi0.x + vi0.y*vi0.y + vi0.z*vi0.z + vi0.w*vi0.w
            + vr1.x*vr1.x + vr1.y*vr1.y + vr1.z*vr1.z + vr1.w*vr1.w
            + vi1.x*vi1.x + vi1.y*vi1.y + vi1.z*vi1.z + vi1.w*vi1.w;
  sr[c*4+0][j0] = vr0.x; sr[c*4+1][j0] = vr0.y; sr[c*4+2][j0] = vr0.z; sr[c*4+3][j0] = vr0.w;
  si[c*4+0][j0] = vi0.x; si[c*4+1][j0] = vi0.y; si[c*4+2][j0] = vi0.z; si[c*4+3][j0] = vi0.w;
  sr[c*4+0][j1] = vr1.x; sr[c*4+1][j1] = vr1.y; sr[c*4+2][j1] = vr1.z; sr[c*4+3][j1] = vr1.w;
  si[c*4+0][j1] = vi1.x; si[c*4+1][j1] = vi1.y; si[c*4+2][j1] = vi1.z; si[c*4+3][j1] = vi1.w;
#pragma unroll
  for (int m = 32; m >= 1; m >>= 1) acc += __shfl_xor(acc, m, 64);
  if (lane == 0) red[w] = acc;
  __syncthreads();
  if (tid == 0) {
    float sm = 0.f;
#pragma unroll
    for (int k = 0; k < 16; ++k) sm += red[k];
    partial[bid] = sm;
  }
  // compute phase: wave w owns rows 2w, 2w+1 (hi contiguous in LDS rows)
#pragma unroll
  for (int r = 0; r < 2; ++r) {
    const int ll = w * 2 + r;
    const float4 a4 = *reinterpret_cast<const float4*>(&sr[ll][lane * 4]);
    const float4 b4 = *reinterpret_cast<const float4*>(&si[ll][lane * 4]);
    float xr[4] = {a4.x, a4.y, a4.z, a4.w};
    float xi[4] = {b4.x, b4.y, b4.z, b4.w};
    wht256(xr, xi, lane);
    const float2 p4 = phh4[lane];
#pragma unroll
    for (int q = 0; q < 4; ++q) {
      const float2 pq = phHQ[q];
      const float pr = p4.x * pq.x - p4.y * pq.y;
      const float pi = p4.x * pq.y + p4.y * pq.x;
      const float ur = xr[q], ui = xi[q];
      xr[q] = ur * pr - ui * pi;
      xi[q] = ur * pi + ui * pr;
    }
    wht256(xr, xi, lane);
    *reinterpret_cast<float4*>(&sr[ll][lane * 4]) = make_float4(xr[0], xr[1], xr[2], xr[3]);
    *reinterpret_cast<float4*>(&si[ll][lane * 4]) = make_float4(xi[0], xi[1], xi[2], xi[3]);
  }
  __syncthreads();
  // store phase: T[b][m_hi][lo] complex interleaved; 4 threads per m_hi row,
  // each instruction writes 64B contiguous (4 lanes x float4)
  float* Tb = T + ((size_t)b << 17);
  const int m = tid >> 2, sub = tid & 3;
  float* dst = Tb + ((size_t)m << 9) + (size_t)lo0 * 2;
#pragma unroll
  for (int j = 0; j < 4; ++j) {
    const int l0 = 8 * j + 2 * sub;
    *reinterpret_cast<float4*>(dst + l0 * 2) =
        make_float4(sr[l0][m], si[l0][m], sr[l0 + 1][m], si[l0 + 1][m]);
  }
}

// K2: A_lo = WHT·diag(ph_lo)·WHT along contiguous lo axis, |.|^2 * iv,
// permuted scatter out[srow[m_hi] ^ sloL[lane] ^ sloQ[q]] (lo-varying = the
// empirically fast orientation). GF(2)/phase linearity factors all tables to
// one conflict-free LDS read per lane. XCD swizzle: each XCD owns 16 batches.
__global__ __launch_bounds__(256, 8) void k2_alo_scatter(const float* __restrict__ T,
                                                         const float* __restrict__ thetas,
                                                         const int* __restrict__ cnot,
                                                         const float* __restrict__ partial,
                                                         float* __restrict__ outp) {
  __shared__ float2 phl4[64];
  __shared__ float2 phLQ[4];
  __shared__ int sloL[64];
  __shared__ int tj[16];
  __shared__ int srow16[16];
  __shared__ float th[16];
  __shared__ float shinv;
  const int bid = blockIdx.x;
  const int x = bid & 7, s2 = bid >> 3;
  const int b = x * 16 + (s2 >> 4), tile = s2 & 15;
  const int tid = threadIdx.x, lane = tid & 63, w = tid >> 6;
  if (tid < 16) {
    th[tid] = thetas[b * 16 + tid];
    int v = 0;
#pragma unroll
    for (int i = 0; i < 16; ++i) v |= ((cnot[1 << i] >> tid) & 1) << i;
    tj[tid] = v;
  }
  if (tid == 0) {
    float sum = 0.f;
#pragma unroll
    for (int k = 0; k < 8; ++k) sum += partial[b * 8 + k];
    shinv = 1.0f / (sum * 4294967296.0f);  // fold 2^-32 WHT scaling + 1/norm^2
  }
  __syncthreads();
  if (tid < 64) {
    float a = 0.f;
#pragma unroll
    for (int i = 0; i < 6; ++i)
      if ((tid >> (5 - i)) & 1) a += th[8 + i];
    phl4[tid] = make_float2(cosf(0.5f * a), -sinf(0.5f * a));
    int v = 0;
#pragma unroll
    for (int bb = 0; bb < 6; ++bb)
      if ((tid >> bb) & 1) v ^= tj[2 + bb];
    sloL[tid] = v;
    if (tid < 4) {
      float aq = 0.f;
      if (tid & 1) aq += th[15];
      if (tid & 2) aq += th[14];
      phLQ[tid] = make_float2(cosf(0.5f * aq), -sinf(0.5f * aq));
    }
  }
  if (tid < 16) {
    const int mh = tile * 16 + tid;
    int v = 0;
#pragma unroll
    for (int bb = 0; bb < 8; ++bb)
      if ((mh >> bb) & 1) v ^= tj[8 + bb];
    srow16[tid] = v;
  }
  __syncthreads();
  const float* Tb = T + ((size_t)b << 17);
  float* ob = outp + ((size_t)b << 16);
  const float iv = shinv;
  const float2 p4 = phl4[lane];
  const int sL = sloL[lane];
  const int sq1 = tj[0], sq2 = tj[1], sq3 = tj[0] ^ tj[1];
  float2 p4q[4];
#pragma unroll
  for (int q = 0; q < 4; ++q) {
    const float2 pq = phLQ[q];
    p4q[q].x = p4.x * pq.x - p4.y * pq.y;
    p4q[q].y = p4.x * pq.y + p4.y * pq.x;
  }
#pragma unroll
  for (int r = 0; r < 4; ++r) {
    const int rl = w * 4 + r;
    const int mh = tile * 16 + rl;
    const float4 va = *reinterpret_cast<const float4*>(Tb + ((size_t)mh << 9) + lane * 8);
    const float4 vb = *reinterpret_cast<const float4*>(Tb + ((size_t)mh << 9) + lane * 8 + 4);
    float xr[4] = {va.x, va.z, vb.x, vb.z};
    float xi[4] = {va.y, va.w, vb.y, vb.w};
    wht256(xr, xi, lane);
#pragma unroll
    for (int q = 0; q < 4; ++q) {
      const float ur = xr[q], ui = xi[q];
      xr[q] = ur * p4q[q].x - ui * p4q[q].y;
      xi[q] = ur * p4q[q].y + ui * p4q[q].x;
    }
    wht256(xr, xi, lane);
    const int base = srow16[rl] ^ sL;
    ob[base]       = (xr[0] * xr[0] + xi[0] * xi[0]) * iv;
    ob[base ^ sq1] = (xr[1] * xr[1] + xi[1] * xi[1]) * iv;
    ob[base ^ sq2] = (xr[2] * xr[2] + xi[2] * xi[2]) * iv;
    ob[base ^ sq3] = (xr[3] * xr[3] + xi[3] * xi[3]) * iv;
  }
}

extern "C" void kernel_launch(void* const* d_in, const int* in_sizes, int n_in,
                              void* d_out, int out_size, void* d_ws, size_t ws_size,
                              hipStream_t stream) {
  const float* sre = (const float*)d_in[0];
  const float* sim = (const float*)d_in[1];
  const float* thetas = (const float*)d_in[2];
  const int* cnot = (const int*)d_in[3];
  float* outp = (float*)d_out;
  char* w = (char*)d_ws;
  const size_t CPLANE = (size_t)NB * NS * 2 * sizeof(float);  // 64 MB complex
  if (ws_size < CPLANE + 8192) return;  // need 64 MB scratch + partials
  float* T = (float*)(w);
  float* partial = (float*)(w + CPLANE);  // 1024 floats

  hipLaunchKernelGGL(k1_ahi, dim3(1024), dim3(1024), 0, stream, sre, sim, thetas, T, partial);
  hipLaunchKernelGGL(k2_alo_scatter, dim3(2048), dim3(256), 0, stream, T, thetas, cnot, partial, outp);
}